// Round 1
// baseline (119.962 us; speedup 1.0000x reference)
//
#include <hip/hip_runtime.h>
#include <stdint.h>

// ---------------------------------------------------------------------------
// DetectorKmeans: out[n] = sum_k (pr[k]*var[k]) / ||X[n]-C[k]||^2  - threshold
// N=65536, K=1024, D=512, all fp32 in/out.
// Round 13: split the single 512-thread block (1 block/CU, every barrier
// drains the whole CU) into 256-thread blocks with BK=32 double-buffer so
// TWO independent blocks co-reside per CU (LDS 50 KB, 244 regs = 2 w/SIMD).
// Per-wave geometry (128x64 output, 0.0234 LDS-B/FLOP) is kept verbatim;
// barrier/vmcnt drains of one block now overlap the other block's MFMA.
// ---------------------------------------------------------------------------

#define NR 65536
#define KC 1024
#define DD 512

#define BM 128
#define BN 256
#define BK 32
#define NKT (DD / BK)     // 16 K-tiles
#define NPART (KC / BN)   // 4 column panels

#define SLOT_SZ 24576     // A 128x32x2 (8 KB) + B 256x32x2 (16 KB)
#define PART_OFF 49152    // after 2 slots
#define LDS_TOTAL (PART_OFF + 2048)   // + [4][128] f32 partial = 51200 B

typedef __bf16 bf16;
typedef __attribute__((ext_vector_type(4))) __bf16 bf16x4;
typedef __attribute__((ext_vector_type(8))) __bf16 bf16x8;
typedef __attribute__((ext_vector_type(4))) float f32x4;

__device__ __forceinline__ void gload16(const void* g, void* l) {
  __builtin_amdgcn_global_load_lds(
      (const __attribute__((address_space(1))) unsigned int*)g,
      (__attribute__((address_space(3))) unsigned int*)l, 16, 0, 0);
}

// ---------------------------------------------------------------------------
__global__ __launch_bounds__(256) void prep_kernel(
    const float* __restrict__ X, const float* __restrict__ C,
    const float* __restrict__ var, const float* __restrict__ pr,
    bf16* __restrict__ Xb, bf16* __restrict__ Cb,
    float* __restrict__ xsq, float* __restrict__ csq, float* __restrict__ w) {
  const int row  = (int)((blockIdx.x * 256 + threadIdx.x) >> 6);
  const int lane = (int)(threadIdx.x & 63);
  const bool isX = row < NR;
  const float* srow = isX ? (X + (size_t)row * DD) : (C + (size_t)(row - NR) * DD);
  bf16* drow = isX ? (Xb + (size_t)row * DD) : (Cb + (size_t)(row - NR) * DD);

  float4 a = reinterpret_cast<const float4*>(srow)[lane];
  float4 b = reinterpret_cast<const float4*>(srow)[64 + lane];
  float s = a.x * a.x + a.y * a.y + a.z * a.z + a.w * a.w +
            b.x * b.x + b.y * b.y + b.z * b.z + b.w * b.w;
#pragma unroll
  for (int off = 1; off < 64; off <<= 1) s += __shfl_xor(s, off, 64);

  bf16x4 va = {(bf16)a.x, (bf16)a.y, (bf16)a.z, (bf16)a.w};
  bf16x4 vb = {(bf16)b.x, (bf16)b.y, (bf16)b.z, (bf16)b.w};
  reinterpret_cast<bf16x4*>(drow)[lane]      = va;
  reinterpret_cast<bf16x4*>(drow)[64 + lane] = vb;

  if (lane == 0) {
    if (isX) {
      xsq[row] = s;
    } else {
      const int k = row - NR;
      csq[k] = s;
      w[k]   = pr[k] * var[k];
    }
  }
}

// ---------------------------------------------------------------------------
// LDS per 24 KB slot:
//   A at [0, 8192):    128 rows x 64 B (BK=32); row r's 16-B chunk c lives at
//                      slot c ^ ((r>>1)&3)  (2-way conflict-free b128 reads).
//   B at [8192,24576): 256 cols x 64 B, same chunk swizzle on (col>>1)&3.
//   Pre-swizzled gload source, linear DMA dest (wave-uniform base + lane*16).
// ---------------------------------------------------------------------------

#define STAGE(tn, slotW)                                                        \
  gload16(aSrc0 + (tn) * 32,                smem + (slotW) + wid * 1024);       \
  gload16(aSrc0 + (size_t)64 * DD + (tn) * 32,                                  \
          smem + (slotW) + 4096 + wid * 1024);                                  \
  gload16(bSrc0 + (tn) * 32,                smem + (slotW) + 8192 + wid * 1024);\
  gload16(bSrc0 + (size_t)64 * DD + (tn) * 32,                                  \
          smem + (slotW) + 12288 + wid * 1024);                                 \
  gload16(bSrc0 + (size_t)128 * DD + (tn) * 32,                                 \
          smem + (slotW) + 16384 + wid * 1024);                                 \
  gload16(bSrc0 + (size_t)192 * DD + (tn) * 32,                                 \
          smem + (slotW) + 20480 + wid * 1024);

__global__ __launch_bounds__(256, 2) void density_kernel(
    const bf16* __restrict__ Xb, const bf16* __restrict__ Cb,
    const float* __restrict__ xsq, const float* __restrict__ csq,
    const float* __restrict__ w, float* __restrict__ partial) {
  extern __shared__ char smem[];

  const int tid  = (int)threadIdx.x;
  const int lane = tid & 63;
  const int wid  = tid >> 6;    // 0..3 : 64-col group (wcn)
  const int lr   = lane & 15;
  const int lc   = lane >> 4;

  // XCD-aware bijective swizzle: grid 2048, 8 XCDs, 256 blocks each.
  const int bid   = (int)blockIdx.x;
  const int swz   = (bid & 7) * 256 + (bid >> 3);
  const int ntile = swz >> 9;     // 0..3   (512 m-tiles per panel)
  const int mtile = swz & 511;    // 0..511
  const int rowBase = mtile * BM;
  const int colBase = ntile * BN;

  // staging sources (pre-swizzled chunk; linear DMA dest)
  const int chunkSw = (((lane & 3) ^ ((lane >> 3) & 3)) << 3);
  const bf16* aSrc0 = Xb + (size_t)(rowBase + wid * 16 + (lane >> 2)) * DD + chunkSw;
  const bf16* bSrc0 = Cb + (size_t)(colBase + wid * 16 + (lane >> 2)) * DD + chunkSw;

  // fragment read bases (same XOR on the read side)
  const int rdSw = ((lc ^ ((lr >> 1) & 3)) << 4);
  const int aRd  = lr * 64 + rdSw;                       // + mi*1024
  const int bRd  = 8192 + (wid * 64 + lr) * 64 + rdSw;   // + n*1024

  f32x4 acc[8][4];
#pragma unroll
  for (int m = 0; m < 8; ++m)
#pragma unroll
    for (int n = 0; n < 4; ++n) acc[m][n] = (f32x4){0.f, 0.f, 0.f, 0.f};

  // ---- prologue: stage tile 0 into slot 0 ----
  STAGE(0, 0);
  asm volatile("s_waitcnt vmcnt(0)");
  __builtin_amdgcn_s_barrier();

  // ---- main loop: one phase + one barrier per K-tile ----
#pragma unroll 1
  for (int t = 0; t < NKT; ++t) {
    const int slotR = (t & 1) ? SLOT_SZ : 0;
    const int slotW = slotR ^ SLOT_SZ;
    const int tn = t + 1;
    const bool st = tn < NKT;

    // stage t+1 first (6 gload_lds; full compute phase before the vmcnt)
    if (st) {
      STAGE(tn, slotW);
    }

    // B fragments up front (reused by all 8 A-frags)
    bf16x8 bg[4];
#pragma unroll
    for (int n = 0; n < 4; ++n)
      bg[n] = *(const bf16x8*)(smem + slotR + bRd + n * 1024);

    // stream A-frags; compiler inserts counted lgkm waits
    __builtin_amdgcn_s_setprio(1);
#pragma unroll
    for (int mi = 0; mi < 8; ++mi) {
      const bf16x8 a = *(const bf16x8*)(smem + slotR + aRd + mi * 1024);
#pragma unroll
      for (int n = 0; n < 4; ++n)
        acc[mi][n] = __builtin_amdgcn_mfma_f32_16x16x32_bf16(
            a, bg[n], acc[mi][n], 0, 0, 0);
    }
    __builtin_amdgcn_s_setprio(0);

    if (st) {
      asm volatile("s_waitcnt vmcnt(0)");   // t+1 landed
      __builtin_amdgcn_s_barrier();         // the ONLY barrier per K-tile
    }
  }

  // ---- epilogue: density partials for this wave's 128x64 output ----
  float xr[8][4];
#pragma unroll
  for (int m = 0; m < 8; ++m)
#pragma unroll
    for (int j = 0; j < 4; ++j)
      xr[m][j] = xsq[rowBase + m * 16 + lc * 4 + j];

  float rsum[8][4];
#pragma unroll
  for (int m = 0; m < 8; ++m)
#pragma unroll
    for (int j = 0; j < 4; ++j) rsum[m][j] = 0.f;

#pragma unroll
  for (int n = 0; n < 4; ++n) {
    const int gc = colBase + wid * 64 + n * 16 + lr;
    const float cs = csq[gc];
    const float ww = w[gc];
#pragma unroll
    for (int m = 0; m < 8; ++m)
#pragma unroll
      for (int j = 0; j < 4; ++j) {
        const float sq = xr[m][j] + cs - 2.f * acc[m][n][j];
        rsum[m][j] += ww * __builtin_amdgcn_rcpf(sq);
      }
  }
#pragma unroll
  for (int m = 0; m < 8; ++m)
#pragma unroll
    for (int j = 0; j < 4; ++j) {
      float v = rsum[m][j];
      v += __shfl_xor(v, 1, 64);
      v += __shfl_xor(v, 2, 64);
      v += __shfl_xor(v, 4, 64);
      v += __shfl_xor(v, 8, 64);
      rsum[m][j] = v;
    }

  float* part = (float*)(smem + PART_OFF);   // [4 wid][128 rows]
  __syncthreads();
  if (lr == 0) {
#pragma unroll
    for (int m = 0; m < 8; ++m)
#pragma unroll
      for (int j = 0; j < 4; ++j)
        part[wid * 128 + m * 16 + lc * 4 + j] = rsum[m][j];
  }
  __syncthreads();
  if (tid < BM) {
    const float s = part[tid] + part[128 + tid] + part[256 + tid] + part[384 + tid];
    partial[(size_t)ntile * NR + rowBase + tid] = s;
  }
}

// ---------------------------------------------------------------------------
__global__ __launch_bounds__(256) void reduce_kernel(
    const float* __restrict__ partial, const float* __restrict__ thr,
    float* __restrict__ out) {
  const int n = (int)(blockIdx.x * 256 + threadIdx.x);
  float s = 0.f;
#pragma unroll
  for (int g = 0; g < NPART; ++g) s += partial[(size_t)g * NR + n];
  out[n] = s - thr[0];
}

// ---------------------------------------------------------------------------
extern "C" void kernel_launch(void* const* d_in, const int* in_sizes, int n_in,
                              void* d_out, int out_size, void* d_ws, size_t ws_size,
                              hipStream_t stream) {
  const float* X   = (const float*)d_in[0];
  const float* C   = (const float*)d_in[1];
  const float* var = (const float*)d_in[2];
  const float* pr  = (const float*)d_in[3];
  const float* thr = (const float*)d_in[4];
  float* out = (float*)d_out;

  char* ws = (char*)d_ws;
  bf16* Xb   = (bf16*)(ws);
  bf16* Cb   = (bf16*)(ws + (size_t)NR * DD * 2);
  float* xsq = (float*)(ws + (size_t)NR * DD * 2 + (size_t)KC * DD * 2);
  float* csq = xsq + NR;
  float* w   = csq + KC;
  float* partial = w + KC;   // 4 * 65536 floats = 1 MB

  prep_kernel<<<(NR + KC) / 4, 256, 0, stream>>>(X, C, var, pr, Xb, Cb, xsq, csq, w);
  density_kernel<<<(NR / BM) * NPART, 256, LDS_TOTAL, stream>>>(
      Xb, Cb, xsq, csq, w, partial);
  reduce_kernel<<<NR / 256, 256, 0, stream>>>(partial, thr, out);
}